// Round 1
// baseline (163.063 us; speedup 1.0000x reference)
//
#include <hip/hip_runtime.h>
#include <hip/hip_bf16.h>
#include <stdint.h>

#define M_DIM 4096
#define N_DIM 4096
#define K_DIM 2048

typedef __bf16 bf16x8 __attribute__((ext_vector_type(8)));
typedef float f32x4 __attribute__((ext_vector_type(4)));
typedef unsigned short u16x8 __attribute__((ext_vector_type(8)));

// ---------------- fp32 -> bf16 (RNE) ----------------
__device__ __forceinline__ unsigned short f32_to_bf16(float f) {
  union { float f; unsigned int u; } c; c.f = f;
  unsigned int u = c.u;
  unsigned int r = (u + 0x7FFFu + ((u >> 16) & 1u)) >> 16;
  return (unsigned short)r;
}

// Convert BOTH tensors fp32->bf16 with the XOR column-granule swizzle
// (granule g of row r within each 64-col K-tile holds source granule
// g ^ (r&7)) so the forced-linear global_load_lds staging yields a
// bank-conflict-free LDS tile. Block 0 additionally zeroes S.
__global__ void __launch_bounds__(256) cvt_swz_kernel(
    const float* __restrict__ x, const float* __restrict__ w,
    unsigned short* __restrict__ xb, unsigned short* __restrict__ wb,
    float* __restrict__ S) {
  if (blockIdx.x == 0) {
#pragma unroll
    for (int k = 0; k < 16; ++k)
      S[threadIdx.x + k * 256] = 0.f;
  }

  const int nG = M_DIM * K_DIM / 8;  // granules per tensor
  int i = blockIdx.x * 256 + threadIdx.x;
  const float* src;
  unsigned short* dst;
  int gid;
  if (i < nG) { src = x; dst = xb; gid = i; }
  else        { src = w; dst = wb; gid = i - nG; }

  const int row = gid >> 8;        // K/8 = 256 granules per row
  const int cg  = gid & 255;
  const int kt  = cg >> 3;
  const int g   = cg & 7;
  const int sg  = g ^ (row & 7);   // swizzled source granule

  const float4* s4 = (const float4*)(src + (size_t)row * K_DIM + kt * 64 + sg * 8);
  float4 f0 = s4[0], f1 = s4[1];
  u16x8 o;
  o[0] = f32_to_bf16(f0.x); o[1] = f32_to_bf16(f0.y);
  o[2] = f32_to_bf16(f0.z); o[3] = f32_to_bf16(f0.w);
  o[4] = f32_to_bf16(f1.x); o[5] = f32_to_bf16(f1.y);
  o[6] = f32_to_bf16(f1.z); o[7] = f32_to_bf16(f1.w);
  ((u16x8*)dst)[gid] = o;
}

// ---------------- async global -> LDS, 16B per lane ----------------
__device__ __forceinline__ void gload_lds16(const unsigned short* g, unsigned short* l) {
  __builtin_amdgcn_global_load_lds(
      (const __attribute__((address_space(1))) unsigned int*)g,
      (__attribute__((address_space(3))) unsigned int*)l,
      16, 0, 0);
}

#define MFMA16(A, B, C) __builtin_amdgcn_mfma_f32_16x16x32_bf16((A), (B), (C), 0, 0, 0)

// LDS fragment read honoring the XOR granule swizzle (row&7 == lr&7 because
// all row offsets added to lr are multiples of 16).
#define RD_FRAG(P, ROW, KS) \
  (*(const bf16x8*)((P) + (ROW) * 64 + ((((KS) * 4 + q) ^ (lr & 7)) * 8)))

// One phase's sync + MFMA cluster: convoy barrier, wait own ds_reads
// (sched_barrier(0) per rule #18 so MFMAs can't hoist above the wait),
// setprio(1) around the 16 MFMAs (T5), optional trailing convoy barrier.
#define PHASE_TAIL(N0, N1, ENDBAR)                                  \
    __builtin_amdgcn_s_barrier();                                   \
    asm volatile("s_waitcnt lgkmcnt(0)" ::: "memory");              \
    __builtin_amdgcn_sched_barrier(0);                              \
    __builtin_amdgcn_s_setprio(1);                                  \
    _Pragma("unroll")                                               \
    for (int mi = 0; mi < 4; ++mi) {                                \
      acc[mi][N0] = MFMA16(a[mi][0], b0, acc[mi][N0]);              \
      acc[mi][N1] = MFMA16(a[mi][0], b2, acc[mi][N1]);              \
      acc[mi][N0] = MFMA16(a[mi][1], b1, acc[mi][N0]);              \
      acc[mi][N1] = MFMA16(a[mi][1], b3, acc[mi][N1]);              \
    }                                                               \
    __builtin_amdgcn_s_setprio(0);                                  \
    if (ENDBAR) __builtin_amdgcn_s_barrier();

// One K-tile = 4 phases (C col-pairs). A frags (8) are loaded once in phase 0
// and stay register-resident, so A[cur] is dead after phase 0's closing
// barrier; B call c (64 rows) is dead after phase (c&1)*2+1. Staging for
// tile T+2 (into the buffer THIS tile reads) is placed strictly after the
// barrier that retires its region's last reader:
//   phase0: B(T+1) calls 1,3  -> other buffer (last read: tile T-1 phase 3)
//   phase1: A(T+2) calls 0,1  -> this buffer  (A dead after phase 0)
//   phase2: A(T+2) calls 2,3 + B(T+2) calls 0,2 (dead after phase 1)
// Phase 3 has no trailing barrier: it merges with the loop-top
// vmcnt(6)+s_barrier of the next tile.
#define TILE_BODY(AP, BP, DO_S1, DO_S2, T)                                   \
  {                                                                          \
    _Pragma("unroll")                                                        \
    for (int mi = 0; mi < 4; ++mi) {                                         \
      a[mi][0] = RD_FRAG(AP, wr + mi * 16 + lr, 0);                          \
      a[mi][1] = RD_FRAG(AP, wr + mi * 16 + lr, 1);                          \
    }                                                                        \
    {                                                                        \
      bf16x8 b0 = RD_FRAG(BP, wc + 0 * 16 + lr, 0);                          \
      bf16x8 b1 = RD_FRAG(BP, wc + 0 * 16 + lr, 1);                          \
      bf16x8 b2 = RD_FRAG(BP, wc + 1 * 16 + lr, 0);                          \
      bf16x8 b3 = RD_FRAG(BP, wc + 1 * 16 + lr, 1);                          \
      if (DO_S1) { stage_b((T) + 1, 1); stage_b((T) + 1, 3); }               \
      PHASE_TAIL(0, 1, true)                                                 \
    }                                                                        \
    {                                                                        \
      bf16x8 b0 = RD_FRAG(BP, wc + 2 * 16 + lr, 0);                          \
      bf16x8 b1 = RD_FRAG(BP, wc + 2 * 16 + lr, 1);                          \
      bf16x8 b2 = RD_FRAG(BP, wc + 3 * 16 + lr, 0);                          \
      bf16x8 b3 = RD_FRAG(BP, wc + 3 * 16 + lr, 1);                          \
      if (DO_S2) { stage_a((T) + 2, 0); stage_a((T) + 2, 1); }               \
      PHASE_TAIL(2, 3, true)                                                 \
    }                                                                        \
    {                                                                        \
      bf16x8 b0 = RD_FRAG(BP, wc + 4 * 16 + lr, 0);                          \
      bf16x8 b1 = RD_FRAG(BP, wc + 4 * 16 + lr, 1);                          \
      bf16x8 b2 = RD_FRAG(BP, wc + 5 * 16 + lr, 0);                          \
      bf16x8 b3 = RD_FRAG(BP, wc + 5 * 16 + lr, 1);                          \
      if (DO_S2) { stage_a((T) + 2, 2); stage_a((T) + 2, 3);                 \
                   stage_b((T) + 2, 0); stage_b((T) + 2, 2); }               \
      PHASE_TAIL(4, 5, true)                                                 \
    }                                                                        \
    {                                                                        \
      bf16x8 b0 = RD_FRAG(BP, wc + 6 * 16 + lr, 0);                          \
      bf16x8 b1 = RD_FRAG(BP, wc + 6 * 16 + lr, 1);                          \
      bf16x8 b2 = RD_FRAG(BP, wc + 7 * 16 + lr, 0);                          \
      bf16x8 b3 = RD_FRAG(BP, wc + 7 * 16 + lr, 1);                          \
      PHASE_TAIL(6, 7, false)                                                \
    }                                                                        \
  }

// ---------------- fused GEMM -> clamp -> sum exp(v-10) per row ----------------
// 256x256 block tile, 512 threads = 8 waves, each wave 64x128 (4x8 frags of
// 16x16x32 bf16). 8-phase counted-vmcnt schedule (T3+T4+T5): the main loop
// NEVER drains vmcnt to 0 — loop-top s_waitcnt vmcnt(6) retires exactly the
// 8 DMA of the tile about to be computed while 6 newer DMA (next tiles) stay
// in flight across all barriers. Steady-state vmcnt math (2 gload calls per
// 64-row "call", 8 calls/tile): at loop top, outstanding = 6 (A(t+1)x4,
// B(t+1) calls 0,2) + 8 issued during t-1 (B(t)1,3 | A(t+1)0,1 |
// A(t+1)2,3+B(t+1)0,2) = 14; vmcnt(6) retires the oldest 8 = all of tile t.
__global__ void __launch_bounds__(512, 2) gemm_lse_kernel(
    const unsigned short* __restrict__ xb,   // [M][K] bf16, swizzled granules
    const unsigned short* __restrict__ wb,   // [N][K] bf16, swizzled granules
    const float* __restrict__ bias,          // [N]
    float* __restrict__ S) {                 // [M] partial sums of exp(clamp(v)-10)
  extern __shared__ __align__(16) unsigned short lds[];
  // As: lds[0..16383] / lds[16384..32767]; Bs: +32768 (shorts), 32 KB each.

  const int tid = threadIdx.x;
  const int bm0 = blockIdx.y * 256;
  const int bn0 = blockIdx.x * 256;

  const int wave = tid >> 6, lane = tid & 63;
  const int wr = (wave & 3) * 64;    // wave row offset (0..192)
  const int wc = (wave >> 2) * 128;  // wave col offset (0/128)
  const int lr = lane & 15;
  const int q  = lane >> 4;

  f32x4 acc[4][8];
  const f32x4 zero = {0.f, 0.f, 0.f, 0.f};
#pragma unroll
  for (int mi = 0; mi < 4; ++mi)
#pragma unroll
    for (int ni = 0; ni < 8; ++ni)
      acc[mi][ni] = zero;

  bf16x8 a[4][2];                   // A frags, register-resident per tile

  const int srow = tid >> 3;        // 0..63
  const int scol = (tid & 7) * 8;

  const unsigned short* xg = xb + (size_t)(bm0 + srow) * K_DIM + scol;
  const unsigned short* wg = wb + (size_t)(bn0 + srow) * K_DIM + scol;
  unsigned short* lA = lds + tid * 8;            // A staging base (+16384 buf1)
  unsigned short* lB = lds + 32768 + tid * 8;    // B staging base (+16384 buf1)

  // stage call c = rows 64c..64c+63 of operand tile tt into buf[tt&1]
  auto stage_a = [&](int tt, int c) {
    gload_lds16(xg + (size_t)(c * 64) * K_DIM + tt * 64,
                lA + (tt & 1) * 16384 + c * 64 * 64);
  };
  auto stage_b = [&](int tt, int c) {
    gload_lds16(wg + (size_t)(c * 64) * K_DIM + tt * 64,
                lB + (tt & 1) * 16384 + c * 64 * 64);
  };

  // Prologue: tile0 complete (8) + A(1) x4 + B(1) calls 0,2  -> 14 in flight,
  // matching the steady-state shape the loop-top vmcnt(6) expects.
#pragma unroll
  for (int c = 0; c < 4; ++c) { stage_a(0, c); stage_b(0, c); }
#pragma unroll
  for (int c = 0; c < 4; ++c) stage_a(1, c);
  stage_b(1, 0); stage_b(1, 2);

  for (int t = 0; t < 31; ++t) {
    const unsigned short* As = lds + (t & 1) * 16384;
    const unsigned short* Bs = lds + 32768 + (t & 1) * 16384;
    const bool s2 = (t < 30);  // tile t+2 exists
    asm volatile("s_waitcnt vmcnt(6)" ::: "memory");
    __builtin_amdgcn_sched_barrier(0);
    __builtin_amdgcn_s_barrier();
    TILE_BODY(As, Bs, true, s2, t)
  }
  {  // peeled last tile (t=31): nothing left to stage, full drain is fine
    const unsigned short* As = lds + 16384;
    const unsigned short* Bs = lds + 32768 + 16384;
    asm volatile("s_waitcnt vmcnt(0)" ::: "memory");
    __builtin_amdgcn_sched_barrier(0);
    __builtin_amdgcn_s_barrier();
    TILE_BODY(As, Bs, false, false, 31)
  }

  // Epilogue: bias + clamp + exp(v-10); reduce across 16 lanes (128 cols);
  // one fire-and-forget atomic per row per wave (32 contributions/row total).
  float bv[8];
#pragma unroll
  for (int ni = 0; ni < 8; ++ni)
    bv[ni] = bias[bn0 + wc + ni * 16 + lr];

#pragma unroll
  for (int mi = 0; mi < 4; ++mi) {
#pragma unroll
    for (int reg = 0; reg < 4; ++reg) {
      float s = 0.f;
#pragma unroll
      for (int ni = 0; ni < 8; ++ni) {
        float v = acc[mi][ni][reg] + bv[ni];  // SCALE_FACTOR*2 == 1.0
        v = fminf(fmaxf(v, -10.f), 10.f);
        s += __expf(v - 10.f);
      }
      s += __shfl_xor(s, 1);
      s += __shfl_xor(s, 2);
      s += __shfl_xor(s, 4);
      s += __shfl_xor(s, 8);
      if (lr == 0)
        atomicAdd(&S[bm0 + wr + mi * 16 + q * 4 + reg], s);
    }
  }
}

// ---------------- finalize: lse = 10 + log(S); mish(lse) ----------------
__global__ void __launch_bounds__(256) finalize_kernel(const float* __restrict__ S,
                                                       float* __restrict__ out) {
  int i = blockIdx.x * blockDim.x + threadIdx.x;
  float lse = 10.0f + logf(S[i]);
  float sp = fmaxf(lse, 0.f) + log1pf(expf(-fabsf(lse)));  // stable softplus
  out[i] = lse * tanhf(sp);
}

extern "C" void kernel_launch(void* const* d_in, const int* in_sizes, int n_in,
                              void* d_out, int out_size, void* d_ws, size_t ws_size,
                              hipStream_t stream) {
  const float* x = (const float*)d_in[0];   // [4096, 2048]
  const float* W = (const float*)d_in[1];   // [4096, 2048]
  const float* b = (const float*)d_in[2];   // [4096]
  float* out = (float*)d_out;               // [4096]

  char* ws = (char*)d_ws;
  float* S = (float*)ws;                                       // 16 KB
  unsigned short* xb = (unsigned short*)(ws + 16384);          // 16 MB
  unsigned short* wb = (unsigned short*)(ws + 16384 + (size_t)M_DIM * K_DIM * 2);

  const int nG2 = 2 * M_DIM * K_DIM / 8;  // both tensors, 16B granules
  cvt_swz_kernel<<<nG2 / 256, 256, 0, stream>>>(x, W, xb, wb, S);

  // 128 KB dynamic LDS needs the opt-in attribute (idempotent, capture-safe).
  hipFuncSetAttribute((const void*)gemm_lse_kernel,
                      hipFuncAttributeMaxDynamicSharedMemorySize, 131072);
  dim3 grid(N_DIM / 256, M_DIM / 256);  // 16 x 16 = 256 blocks, 1/CU
  gemm_lse_kernel<<<grid, 512, 131072, stream>>>(xb, wb, b, S);

  finalize_kernel<<<M_DIM / 256, 256, 0, stream>>>(S, out);
}